// Round 1
// baseline (5086.475 us; speedup 1.0000x reference)
//
#include <hip/hip_runtime.h>
#include <hip/hip_bf16.h>

// Problem: B=8, N=4096, C=256, c4=64. All fp32.
// P = B*N = 32768 points.
//
// Pipeline:
//  x0  = relu(feature @ conv0_w^T + b)            [P,64]
//  idx1 = knn12(x0);  EC1: h1=relu(u1[j]+v1[i]), h2=relu(h1@W2^T+b2), max_k -> x1 [P,256]
//  x1c = relu(x1 @ conv1_w^T + b)                 [P,64]
//  idx2 = knn8(x1c);  EC2: x2 = sum_k relu(u2[j]+v2[i])  [P,256]
//  xd1 = relu(x2 @ dec1^T), xd2 = relu(xd1 @ dec2^T), out = relu(xd2 @ out_w^T + out_b)
//
// u/v decomposition: W=[A|B] (cols 0:64 multiply x_j-x_i, 64:128 multiply x_i)
//   edge(o) = x_j . A[o] + x_i . (B[o]-A[o])  ->  u[j][o] + v[i][o]  (bias folded into v)

#define PTS_TOTAL 32768
#define NPTS 4096
#define NBATCH 8

// ---------------------------------------------------------------- prep weights
__global__ void prep_kernel(const float* __restrict__ w1, const float* __restrict__ b1,
                            const float* __restrict__ w2,
                            const float* __restrict__ ew, const float* __restrict__ eb,
                            float* __restrict__ wuv1, float* __restrict__ buv1,
                            float* __restrict__ wuv2, float* __restrict__ buv2,
                            float* __restrict__ w2t) {
  int tid = blockIdx.x * 256 + threadIdx.x;
  if (tid < 512 * 64) {
    int o = tid / 64, c = tid % 64;
    int orow = o & 255;
    float a  = w1[orow * 128 + c];
    float bb = w1[orow * 128 + 64 + c];
    wuv1[tid] = (o < 256) ? a : (bb - a);
    float a2  = ew[orow * 128 + c];
    float b2p = ew[orow * 128 + 64 + c];
    wuv2[tid] = (o < 256) ? a2 : (b2p - a2);
  }
  if (tid < 512) {
    buv1[tid] = (tid < 256) ? 0.f : b1[tid - 256];
    buv2[tid] = (tid < 256) ? 0.f : eb[tid - 256];
  }
  if (tid < 65536) {
    int o = tid / 256, c = tid % 256;
    w2t[c * 256 + o] = w2[o * 256 + c];
  }
}

// ---------------------------------------------------------------- generic fp32 GEMM
// C[m][o] = act(sum_k A[m][k]*W[o][k] + bias[o]); BM=BN=64, BK=32, 4x4 reg tiles.
template<bool RELU>
__global__ __launch_bounds__(256) void gemm_rowmajor(
    const float* __restrict__ A, const float* __restrict__ W,
    const float* __restrict__ bias, float* __restrict__ Cmat,
    int M, int K, int Cout) {
  __shared__ float As[32][65];
  __shared__ float Bs[32][65];
  int m0 = blockIdx.x * 64;
  int n0 = blockIdx.y * 64;
  int tid = threadIdx.x;
  int tx = tid & 15, ty = tid >> 4;
  float acc[4][4] = {};
  for (int k0 = 0; k0 < K; k0 += 32) {
#pragma unroll
    for (int i = 0; i < 8; ++i) {
      int e = tid + 256 * i;
      int r = e >> 5, c = e & 31;
      As[c][r] = A[(m0 + r) * K + (k0 + c)];
      Bs[c][r] = W[(n0 + r) * K + (k0 + c)];
    }
    __syncthreads();
#pragma unroll
    for (int k = 0; k < 32; ++k) {
      float a[4], b[4];
#pragma unroll
      for (int ii = 0; ii < 4; ++ii) a[ii] = As[k][ty + 16 * ii];
#pragma unroll
      for (int jj = 0; jj < 4; ++jj) b[jj] = Bs[k][tx + 16 * jj];
#pragma unroll
      for (int ii = 0; ii < 4; ++ii)
#pragma unroll
        for (int jj = 0; jj < 4; ++jj)
          acc[ii][jj] += a[ii] * b[jj];
    }
    __syncthreads();
  }
#pragma unroll
  for (int ii = 0; ii < 4; ++ii) {
    int m = m0 + ty + 16 * ii;
#pragma unroll
    for (int jj = 0; jj < 4; ++jj) {
      int n = n0 + tx + 16 * jj;
      float v = acc[ii][jj] + bias[n];
      if (RELU) v = fmaxf(v, 0.f);
      Cmat[(size_t)m * Cout + n] = v;
    }
  }
}

// ---------------------------------------------------------------- squared norms (C=64)
__global__ void sqnorm64(const float* __restrict__ X, float* __restrict__ xx) {
  int p = blockIdx.x * 4 + (threadIdx.x >> 6);
  int lane = threadIdx.x & 63;
  float v = X[(size_t)p * 64 + lane];
  float s = v * v;
#pragma unroll
  for (int off = 32; off >= 1; off >>= 1) s += __shfl_xor(s, off);
  if (lane == 0) xx[p] = s;
}

// ---------------------------------------------------------------- knn (top-KN smallest d' = xx[m]-2*dot)
template<int KN>
__global__ __launch_bounds__(256) void knn_kernel(
    const float* __restrict__ X,   // [B][N][64]
    const float* __restrict__ XX,  // [B][N]
    int* __restrict__ IDX) {       // [B][N][KN] (within-batch indices)
  __shared__ float As[64][65];    // [c][q]
  __shared__ float Bs[64][65];    // [c][m]
  __shared__ float Dbuf[64][65];  // [q][m]  (reused for merge candidates)
  __shared__ float xxs[64];
  int b = blockIdx.y;
  int q0 = blockIdx.x * 64;
  int tid = threadIdx.x;
  const float* Xb = X + (size_t)b * NPTS * 64;
#pragma unroll
  for (int i = 0; i < 16; ++i) {
    int e = tid + 256 * i;
    int r = e >> 6, c = e & 63;
    As[c][r] = Xb[(q0 + r) * 64 + c];
  }
  float bd[KN];
  int bi[KN];
#pragma unroll
  for (int t = 0; t < KN; ++t) { bd[t] = 1e30f; bi[t] = 0x7fffffff; }
  int tx = tid & 15, ty = tid >> 4;
  int q_r = tid >> 2, s_r = tid & 3;
  __syncthreads();
  for (int m0 = 0; m0 < NPTS; m0 += 64) {
#pragma unroll
    for (int i = 0; i < 16; ++i) {
      int e = tid + 256 * i;
      int r = e >> 6, c = e & 63;
      Bs[c][r] = Xb[(m0 + r) * 64 + c];
    }
    if (tid < 64) xxs[tid] = XX[b * NPTS + m0 + tid];
    __syncthreads();
    float acc[4][4] = {};
#pragma unroll
    for (int c = 0; c < 64; ++c) {
      float a[4], bb[4];
#pragma unroll
      for (int ii = 0; ii < 4; ++ii) a[ii] = As[c][ty + 16 * ii];
#pragma unroll
      for (int jj = 0; jj < 4; ++jj) bb[jj] = Bs[c][tx + 16 * jj];
#pragma unroll
      for (int ii = 0; ii < 4; ++ii)
#pragma unroll
        for (int jj = 0; jj < 4; ++jj)
          acc[ii][jj] += a[ii] * bb[jj];
    }
#pragma unroll
    for (int ii = 0; ii < 4; ++ii)
#pragma unroll
      for (int jj = 0; jj < 4; ++jj)
        Dbuf[ty + 16 * ii][tx + 16 * jj] = acc[ii][jj];
    __syncthreads();
#pragma unroll
    for (int i = 0; i < 16; ++i) {
      int m = s_r + 4 * i;
      float d = xxs[m] - 2.0f * Dbuf[q_r][m];
      int gi = m0 + m;
      if (d < bd[KN - 1] || (d == bd[KN - 1] && gi < bi[KN - 1])) {
        bd[KN - 1] = d; bi[KN - 1] = gi;
#pragma unroll
        for (int t = KN - 1; t > 0; --t) {
          bool sw = bd[t] < bd[t - 1] || (bd[t] == bd[t - 1] && bi[t] < bi[t - 1]);
          if (sw) {
            float td = bd[t]; bd[t] = bd[t - 1]; bd[t - 1] = td;
            int ti = bi[t];  bi[t] = bi[t - 1];  bi[t - 1] = ti;
          }
        }
      }
    }
    __syncthreads();
  }
  // merge 4 sorted lists per query
  float* cd = &Dbuf[0][0];
  int* ci = (int*)&As[0][0];
#pragma unroll
  for (int t = 0; t < KN; ++t) {
    cd[q_r * 65 + s_r * KN + t] = bd[t];
    ci[q_r * 65 + s_r * KN + t] = bi[t];
  }
  __syncthreads();
  if (s_r == 0) {
    int p0 = 0, p1 = 0, p2 = 0, p3 = 0;
    int q = q_r;
    int* outp = IDX + ((size_t)b * NPTS + q0 + q) * KN;
    for (int r = 0; r < KN; ++r) {
      float d0 = cd[q * 65 + 0 * KN + p0], d1 = cd[q * 65 + 1 * KN + p1];
      float d2 = cd[q * 65 + 2 * KN + p2], d3 = cd[q * 65 + 3 * KN + p3];
      int i0 = ci[q * 65 + 0 * KN + p0], i1 = ci[q * 65 + 1 * KN + p1];
      int i2 = ci[q * 65 + 2 * KN + p2], i3 = ci[q * 65 + 3 * KN + p3];
      int sel = 0; float bdd = d0; int bii = i0;
      if (d1 < bdd || (d1 == bdd && i1 < bii)) { sel = 1; bdd = d1; bii = i1; }
      if (d2 < bdd || (d2 == bdd && i2 < bii)) { sel = 2; bdd = d2; bii = i2; }
      if (d3 < bdd || (d3 == bdd && i3 < bii)) { sel = 3; bdd = d3; bii = i3; }
      outp[r] = bii;
      if (sel == 0) ++p0; else if (sel == 1) ++p1; else if (sel == 2) ++p2; else ++p3;
    }
  }
}

// ---------------------------------------------------------------- EC1: gather + MLP2 + max
// wave per point; h1[k][c]=relu(u[j_k][c]+v[p][c]) staged in LDS; h2=relu(h1@W2^T+b2); max_k.
__global__ __launch_bounds__(256) void ec1_kernel(
    const float* __restrict__ UV,   // [P][512] (u | v+b1)
    const int* __restrict__ IDX,    // [P][12]
    const float* __restrict__ W2T,  // [256 c][256 o]
    const float* __restrict__ B2,   // [256]
    float* __restrict__ OUT) {      // [P][256]
  __shared__ float h1[4][12][256];
  int wave = threadIdx.x >> 6;
  int lane = threadIdx.x & 63;
  int p = blockIdx.x * 4 + wave;
  int bbase = (p >> 12) << 12;  // batch start point
  const float* uvb = UV + (size_t)bbase * 512;
  const float* vrow = UV + (size_t)p * 512 + 256;
  float v0c[4];
#pragma unroll
  for (int j = 0; j < 4; ++j) v0c[j] = vrow[lane + 64 * j];
#pragma unroll
  for (int k = 0; k < 12; ++k) {
    int jn = IDX[p * 12 + k];
    const float* urow = uvb + (size_t)jn * 512;
#pragma unroll
    for (int j = 0; j < 4; ++j) {
      float hv = urow[lane + 64 * j] + v0c[j];
      h1[wave][k][lane + 64 * j] = fmaxf(hv, 0.f);
    }
  }
  __syncthreads();
  float acc[4][12];
#pragma unroll
  for (int oi = 0; oi < 4; ++oi)
#pragma unroll
    for (int k = 0; k < 12; ++k) acc[oi][k] = 0.f;
  for (int c0 = 0; c0 < 256; c0 += 4) {
    float w[4][4];  // [oi][cj]
#pragma unroll
    for (int cj = 0; cj < 4; ++cj)
#pragma unroll
      for (int oi = 0; oi < 4; ++oi)
        w[oi][cj] = W2T[(size_t)(c0 + cj) * 256 + oi * 64 + lane];
#pragma unroll
    for (int k = 0; k < 12; ++k) {
      float4 h = *(const float4*)&h1[wave][k][c0];
#pragma unroll
      for (int oi = 0; oi < 4; ++oi) {
        acc[oi][k] += h.x * w[oi][0];
        acc[oi][k] += h.y * w[oi][1];
        acc[oi][k] += h.z * w[oi][2];
        acc[oi][k] += h.w * w[oi][3];
      }
    }
  }
#pragma unroll
  for (int oi = 0; oi < 4; ++oi) {
    int o = oi * 64 + lane;
    float m = acc[oi][0];
#pragma unroll
    for (int k = 1; k < 12; ++k) m = fmaxf(m, acc[oi][k]);
    OUT[(size_t)p * 256 + o] = fmaxf(m + B2[o], 0.f);
  }
}

// ---------------------------------------------------------------- EC2: gather + relu + sum
__global__ __launch_bounds__(256) void ec2_kernel(
    const float* __restrict__ UV, const int* __restrict__ IDX,
    float* __restrict__ OUT) {
  int wave = threadIdx.x >> 6;
  int lane = threadIdx.x & 63;
  int p = blockIdx.x * 4 + wave;
  int bbase = (p >> 12) << 12;
  const float* uvb = UV + (size_t)bbase * 512;
  const float* vrow = UV + (size_t)p * 512 + 256;
  float vv[4], acc[4] = {0.f, 0.f, 0.f, 0.f};
#pragma unroll
  for (int j = 0; j < 4; ++j) vv[j] = vrow[lane + 64 * j];
#pragma unroll
  for (int k = 0; k < 8; ++k) {
    int jn = IDX[p * 8 + k];
    const float* urow = uvb + (size_t)jn * 512;
#pragma unroll
    for (int j = 0; j < 4; ++j) acc[j] += fmaxf(urow[lane + 64 * j] + vv[j], 0.f);
  }
#pragma unroll
  for (int j = 0; j < 4; ++j) OUT[(size_t)p * 256 + lane + 64 * j] = acc[j];
}

// ---------------------------------------------------------------- final 64->1
__global__ void final_kernel(const float* __restrict__ X, const float* __restrict__ W,
                             const float* __restrict__ Bb, float* __restrict__ OUT) {
  int p = blockIdx.x * 4 + (threadIdx.x >> 6);
  int lane = threadIdx.x & 63;
  float v = X[(size_t)p * 64 + lane] * W[lane];
#pragma unroll
  for (int off = 32; off >= 1; off >>= 1) v += __shfl_xor(v, off);
  if (lane == 0) OUT[p] = fmaxf(v + Bb[0], 0.f);
}

// ---------------------------------------------------------------- launch
extern "C" void kernel_launch(void* const* d_in, const int* in_sizes, int n_in,
                              void* d_out, int out_size, void* d_ws, size_t ws_size,
                              hipStream_t stream) {
  const float* feature = (const float*)d_in[0];
  const float* conv0_w = (const float*)d_in[1];
  const float* conv0_b = (const float*)d_in[2];
  const float* ec1_w1  = (const float*)d_in[3];
  const float* ec1_b1  = (const float*)d_in[4];
  const float* ec1_w2  = (const float*)d_in[5];
  const float* ec1_b2  = (const float*)d_in[6];
  const float* conv1_w = (const float*)d_in[7];
  const float* conv1_b = (const float*)d_in[8];
  const float* ec2_w   = (const float*)d_in[9];
  const float* ec2_b   = (const float*)d_in[10];
  const float* dec1_w  = (const float*)d_in[11];
  const float* dec1_b  = (const float*)d_in[12];
  const float* dec2_w  = (const float*)d_in[13];
  const float* dec2_b  = (const float*)d_in[14];
  const float* out_w   = (const float*)d_in[15];
  const float* out_b   = (const float*)d_in[16];
  float* out = (float*)d_out;

  char* ws = (char*)d_ws;
  float* wuv1 = (float*)(ws + 0);
  float* buv1 = (float*)(ws + 131072);
  float* wuv2 = (float*)(ws + 133120);
  float* buv2 = (float*)(ws + 264192);
  float* w2t  = (float*)(ws + 266240);
  float* xx   = (float*)(ws + 528384);
  int*   idx  = (int*)  (ws + 659456);
  float* x0   = (float*)(ws + 2232320);   // 8 MB: x0 -> x1c -> xd2
  float* uv   = (float*)(ws + 10620928);  // 64 MB: uv1 -> uv2 -> xd1
  float* x1   = (float*)(ws + 77729792);  // 32 MB: x1 -> x2

  const int P = PTS_TOTAL;

  prep_kernel<<<256, 256, 0, stream>>>(ec1_w1, ec1_b1, ec1_w2, ec2_w, ec2_b,
                                       wuv1, buv1, wuv2, buv2, w2t);
  // conv0: [P,256] -> [P,64]
  gemm_rowmajor<true><<<dim3(P / 64, 1), 256, 0, stream>>>(feature, conv0_w, conv0_b, x0, P, 256, 64);
  sqnorm64<<<P / 4, 256, 0, stream>>>(x0, xx);
  knn_kernel<12><<<dim3(NPTS / 64, NBATCH), 256, 0, stream>>>(x0, xx, idx);
  // uv1: [P,64] -> [P,512]
  gemm_rowmajor<false><<<dim3(P / 64, 8), 256, 0, stream>>>(x0, wuv1, buv1, uv, P, 64, 512);
  ec1_kernel<<<P / 4, 256, 0, stream>>>(uv, idx, w2t, ec1_b2, x1);
  // conv1: [P,256] -> [P,64]
  gemm_rowmajor<true><<<dim3(P / 64, 1), 256, 0, stream>>>(x1, conv1_w, conv1_b, x0, P, 256, 64);
  sqnorm64<<<P / 4, 256, 0, stream>>>(x0, xx);
  knn_kernel<8><<<dim3(NPTS / 64, NBATCH), 256, 0, stream>>>(x0, xx, idx);
  // uv2
  gemm_rowmajor<false><<<dim3(P / 64, 8), 256, 0, stream>>>(x0, wuv2, buv2, uv, P, 64, 512);
  ec2_kernel<<<P / 4, 256, 0, stream>>>(uv, idx, x1);
  // decoder
  float* xd1 = uv;  // uv dead
  gemm_rowmajor<true><<<dim3(P / 64, 2), 256, 0, stream>>>(x1, dec1_w, dec1_b, xd1, P, 256, 128);
  float* xd2 = x0;  // x1c dead
  gemm_rowmajor<true><<<dim3(P / 64, 1), 256, 0, stream>>>(xd1, dec2_w, dec2_b, xd2, P, 128, 64);
  final_kernel<<<P / 4, 256, 0, stream>>>(xd2, out_w, out_b, out);
}

// Round 2
// 3866.776 us; speedup vs baseline: 1.3154x; 1.3154x over previous
//
#include <hip/hip_runtime.h>
#include <hip/hip_bf16.h>

// Problem: B=8, N=4096, C=256, c4=64. All fp32. P = B*N = 32768 points.
//
//  x0  = relu(feature @ conv0_w^T + b)            [P,64]
//  idx1 = knn12(x0);  EC1: h1=relu(u1[j]+v1[i]), h2=relu(h1@W2^T+b2), max_k -> x1 [P,256]
//  x1c = relu(x1 @ conv1_w^T + b)                 [P,64]
//  idx2 = knn8(x1c);  EC2: x2 = sum_k relu(u2[j]+v2[i])  [P,256]
//  decoder: 256->128->64->1 (all relu)
//
// u/v decomposition: W=[A|B]: edge(o) = x_j.A[o] + x_i.(B[o]-A[o]) = u[j][o] + v[i][o]

#define PTS_TOTAL 32768
#define NPTS 4096
#define NBATCH 8

// ---------------------------------------------------------------- prep weights
__global__ void prep_kernel(const float* __restrict__ w1, const float* __restrict__ b1,
                            const float* __restrict__ w2,
                            const float* __restrict__ ew, const float* __restrict__ eb,
                            float* __restrict__ wuv1, float* __restrict__ buv1,
                            float* __restrict__ wuv2, float* __restrict__ buv2,
                            float* __restrict__ w2t) {
  int tid = blockIdx.x * 256 + threadIdx.x;
  if (tid < 512 * 64) {
    int o = tid / 64, c = tid % 64;
    int orow = o & 255;
    float a  = w1[orow * 128 + c];
    float bb = w1[orow * 128 + 64 + c];
    wuv1[tid] = (o < 256) ? a : (bb - a);
    float a2  = ew[orow * 128 + c];
    float b2p = ew[orow * 128 + 64 + c];
    wuv2[tid] = (o < 256) ? a2 : (b2p - a2);
  }
  if (tid < 512) {
    buv1[tid] = (tid < 256) ? 0.f : b1[tid - 256];
    buv2[tid] = (tid < 256) ? 0.f : eb[tid - 256];
  }
  if (tid < 65536) {
    int o = tid / 256, c = tid % 256;
    w2t[c * 256 + o] = w2[o * 256 + c];
  }
}

// ---------------------------------------------------------------- generic fp32 GEMM
// C[m][o] = act(sum_k A[m][k]*W[o][k] + bias[o]); BM=BN=64, BK=32, contiguous 4x4 tiles.
template<bool RELU>
__global__ __launch_bounds__(256) void gemm_rowmajor(
    const float* __restrict__ A, const float* __restrict__ W,
    const float* __restrict__ bias, float* __restrict__ Cmat,
    int M, int K, int Cout) {
  __shared__ __align__(16) float As[32][68];
  __shared__ __align__(16) float Bs[32][68];
  int m0 = blockIdx.x * 64;
  int n0 = blockIdx.y * 64;
  int tid = threadIdx.x;
  int tx = tid & 15, ty = tid >> 4;
  float acc[4][4] = {};
  for (int k0 = 0; k0 < K; k0 += 32) {
    // stage: 64 rows x 32 k, float4 global loads, transposed scalar LDS writes
#pragma unroll
    for (int i = 0; i < 2; ++i) {
      int rr = (tid >> 3) + 32 * i;
      int cc = (tid & 7) * 4;
      float4 va = *(const float4*)&A[(size_t)(m0 + rr) * K + k0 + cc];
      float4 vb = *(const float4*)&W[(size_t)(n0 + rr) * K + k0 + cc];
      As[cc + 0][rr] = va.x; As[cc + 1][rr] = va.y; As[cc + 2][rr] = va.z; As[cc + 3][rr] = va.w;
      Bs[cc + 0][rr] = vb.x; Bs[cc + 1][rr] = vb.y; Bs[cc + 2][rr] = vb.z; Bs[cc + 3][rr] = vb.w;
    }
    __syncthreads();
#pragma unroll 8
    for (int k = 0; k < 32; ++k) {
      float4 a4 = *(const float4*)&As[k][ty * 4];
      float4 b4 = *(const float4*)&Bs[k][tx * 4];
      float a[4] = {a4.x, a4.y, a4.z, a4.w};
      float b[4] = {b4.x, b4.y, b4.z, b4.w};
#pragma unroll
      for (int ii = 0; ii < 4; ++ii)
#pragma unroll
        for (int jj = 0; jj < 4; ++jj)
          acc[ii][jj] += a[ii] * b[jj];
    }
    __syncthreads();
  }
  float4 bias4 = *(const float4*)&bias[n0 + tx * 4];
  float bv[4] = {bias4.x, bias4.y, bias4.z, bias4.w};
#pragma unroll
  for (int ii = 0; ii < 4; ++ii) {
    int m = m0 + ty * 4 + ii;
    float4 v4;
    float* vp = (float*)&v4;
#pragma unroll
    for (int jj = 0; jj < 4; ++jj) {
      float v = acc[ii][jj] + bv[jj];
      if (RELU) v = fmaxf(v, 0.f);
      vp[jj] = v;
    }
    *(float4*)&Cmat[(size_t)m * Cout + n0 + tx * 4] = v4;
  }
}

// ---------------------------------------------------------------- squared norms (C=64)
__global__ void sqnorm64(const float* __restrict__ X, float* __restrict__ xx) {
  int p = blockIdx.x * 4 + (threadIdx.x >> 6);
  int lane = threadIdx.x & 63;
  float v = X[(size_t)p * 64 + lane];
  float s = v * v;
#pragma unroll
  for (int off = 32; off >= 1; off >>= 1) s += __shfl_xor(s, off);
  if (lane == 0) xx[p] = s;
}

// ---------------------------------------------------------------- knn v2
// 64q x 64m tiles, contiguous 4x4 reg tiles, d folded at Dbuf write,
// rotation-swizzled Dbuf (conflict-free b128 both directions), quad-gated insert.
template<int KN>
__global__ __launch_bounds__(256) void knn_kernel(
    const float* __restrict__ X,   // [B][N][64]
    const float* __restrict__ XX,  // [B][N]
    int* __restrict__ IDX) {       // [B][N][KN]
  __shared__ __align__(16) float As[64][68];    // [c][q]
  __shared__ __align__(16) float Bs[64][68];    // [c][m]
  __shared__ __align__(16) float Dbuf[64][68];  // [q][m-swizzled], then merge candidates
  __shared__ float xxs[64];
  int b = blockIdx.y;
  int q0 = blockIdx.x * 64;
  int tid = threadIdx.x;
  int tx = tid & 15, ty = tid >> 4;
  const float* Xb = X + (size_t)b * NPTS * 64;
  // stage A (once): float4 global, transposed scalar LDS writes
#pragma unroll
  for (int i = 0; i < 4; ++i) {
    int r = ty + 16 * i;
    float4 v = *(const float4*)&Xb[(size_t)(q0 + r) * 64 + tx * 4];
    As[tx * 4 + 0][r] = v.x; As[tx * 4 + 1][r] = v.y;
    As[tx * 4 + 2][r] = v.z; As[tx * 4 + 3][r] = v.w;
  }
  float bd[KN];
  int bi[KN];
#pragma unroll
  for (int t = 0; t < KN; ++t) { bd[t] = 1e30f; bi[t] = 0x7fffffff; }
  int qsel = tid >> 2, ssel = tid & 3;
  int m0_prev = -1;
  for (int m0 = 0; m0 < NPTS; m0 += 64) {
    // ---- phase 1: stage Bs/xxs for this tile; select from prev tile's Dbuf
#pragma unroll
    for (int i = 0; i < 4; ++i) {
      int r = ty + 16 * i;
      float4 v = *(const float4*)&Xb[(size_t)(m0 + r) * 64 + tx * 4];
      Bs[tx * 4 + 0][r] = v.x; Bs[tx * 4 + 1][r] = v.y;
      Bs[tx * 4 + 2][r] = v.z; Bs[tx * 4 + 3][r] = v.w;
    }
    if (tid < 64) xxs[tid] = XX[b * NPTS + m0 + tid];
    if (m0_prev >= 0) {
#pragma unroll
      for (int t = 0; t < 4; ++t) {
        int p = ssel * 4 + t;                    // physical chunk
        int lc = (p - qsel) & 15;                // logical chunk
        float4 d4 = *(const float4*)&Dbuf[qsel][4 * p];
        int gibase = m0_prev + 4 * lc;
        float mn = fminf(fminf(d4.x, d4.y), fminf(d4.z, d4.w));
        if (mn <= bd[KN - 1]) {
          float dv[4] = {d4.x, d4.y, d4.z, d4.w};
#pragma unroll
          for (int j = 0; j < 4; ++j) {
            float d = dv[j];
            int gi = gibase + j;
            if (d < bd[KN - 1] || (d == bd[KN - 1] && gi < bi[KN - 1])) {
              bd[KN - 1] = d; bi[KN - 1] = gi;
#pragma unroll
              for (int t2 = KN - 1; t2 > 0; --t2) {
                bool sw = bd[t2] < bd[t2 - 1] || (bd[t2] == bd[t2 - 1] && bi[t2] < bi[t2 - 1]);
                if (sw) {
                  float td = bd[t2]; bd[t2] = bd[t2 - 1]; bd[t2 - 1] = td;
                  int ti = bi[t2];  bi[t2] = bi[t2 - 1];  bi[t2 - 1] = ti;
                }
              }
            }
          }
        }
      }
    }
    __syncthreads();
    // ---- phase 2: gemm + d-write
    float acc[4][4] = {};
#pragma unroll 8
    for (int c = 0; c < 64; ++c) {
      float4 a4 = *(const float4*)&As[c][ty * 4];
      float4 b4 = *(const float4*)&Bs[c][tx * 4];
      float a[4] = {a4.x, a4.y, a4.z, a4.w};
      float bb[4] = {b4.x, b4.y, b4.z, b4.w};
#pragma unroll
      for (int ii = 0; ii < 4; ++ii)
#pragma unroll
        for (int jj = 0; jj < 4; ++jj)
          acc[ii][jj] += a[ii] * bb[jj];
    }
    float4 xx4 = *(const float4*)&xxs[tx * 4];
    float xv[4] = {xx4.x, xx4.y, xx4.z, xx4.w};
#pragma unroll
    for (int ii = 0; ii < 4; ++ii) {
      int q = ty * 4 + ii;
      float4 d4;
      float* dp = (float*)&d4;
#pragma unroll
      for (int jj = 0; jj < 4; ++jj) dp[jj] = xv[jj] - 2.0f * acc[ii][jj];
      *(float4*)&Dbuf[q][4 * ((tx + q) & 15)] = d4;   // rotation swizzle
    }
    m0_prev = m0;
    __syncthreads();
  }
  // final tile's selection
  {
#pragma unroll
    for (int t = 0; t < 4; ++t) {
      int p = ssel * 4 + t;
      int lc = (p - qsel) & 15;
      float4 d4 = *(const float4*)&Dbuf[qsel][4 * p];
      int gibase = m0_prev + 4 * lc;
      float mn = fminf(fminf(d4.x, d4.y), fminf(d4.z, d4.w));
      if (mn <= bd[KN - 1]) {
        float dv[4] = {d4.x, d4.y, d4.z, d4.w};
#pragma unroll
        for (int j = 0; j < 4; ++j) {
          float d = dv[j];
          int gi = gibase + j;
          if (d < bd[KN - 1] || (d == bd[KN - 1] && gi < bi[KN - 1])) {
            bd[KN - 1] = d; bi[KN - 1] = gi;
#pragma unroll
            for (int t2 = KN - 1; t2 > 0; --t2) {
              bool sw = bd[t2] < bd[t2 - 1] || (bd[t2] == bd[t2 - 1] && bi[t2] < bi[t2 - 1]);
              if (sw) {
                float td = bd[t2]; bd[t2] = bd[t2 - 1]; bd[t2 - 1] = td;
                int ti = bi[t2];  bi[t2] = bi[t2 - 1];  bi[t2 - 1] = ti;
              }
            }
          }
        }
      }
    }
  }
  __syncthreads();  // all selects done before list-write reuses Dbuf/As
  // merge 4 sorted lists per query
  float* cd = &Dbuf[0][0];
  int* ci = (int*)&As[0][0];
#pragma unroll
  for (int t = 0; t < KN; ++t) {
    cd[qsel * 68 + ssel * KN + t] = bd[t];
    ci[qsel * 68 + ssel * KN + t] = bi[t];
  }
  __syncthreads();
  if (ssel == 0) {
    int p0 = 0, p1 = 0, p2 = 0, p3 = 0;
    int q = qsel;
    int* outp = IDX + ((size_t)b * NPTS + q0 + q) * KN;
    for (int r = 0; r < KN; ++r) {
      float d0 = cd[q * 68 + 0 * KN + p0], d1 = cd[q * 68 + 1 * KN + p1];
      float d2 = cd[q * 68 + 2 * KN + p2], d3 = cd[q * 68 + 3 * KN + p3];
      int i0 = ci[q * 68 + 0 * KN + p0], i1 = ci[q * 68 + 1 * KN + p1];
      int i2 = ci[q * 68 + 2 * KN + p2], i3 = ci[q * 68 + 3 * KN + p3];
      int sel = 0; float bdd = d0; int bii = i0;
      if (d1 < bdd || (d1 == bdd && i1 < bii)) { sel = 1; bdd = d1; bii = i1; }
      if (d2 < bdd || (d2 == bdd && i2 < bii)) { sel = 2; bdd = d2; bii = i2; }
      if (d3 < bdd || (d3 == bdd && i3 < bii)) { sel = 3; bdd = d3; bii = i3; }
      outp[r] = bii;
      if (sel == 0) ++p0; else if (sel == 1) ++p1; else if (sel == 2) ++p2; else ++p3;
    }
  }
}

// ---------------------------------------------------------------- EC1: gather + MLP2 + max
// wave per point; thread owns 4 contiguous outputs o=4*lane..+3 -> coalesced b128 weights.
__global__ __launch_bounds__(256) void ec1_kernel(
    const float* __restrict__ UV,   // [P][512] (u | v+b1)
    const int* __restrict__ IDX,    // [P][12]
    const float* __restrict__ W2T,  // [256 c][256 o]
    const float* __restrict__ B2,   // [256]
    float* __restrict__ OUT) {      // [P][256]
  __shared__ __align__(16) float h1[4][12][256];
  int wave = threadIdx.x >> 6;
  int lane = threadIdx.x & 63;
  int p = blockIdx.x * 4 + wave;
  int bbase = (p >> 12) << 12;  // batch start point
  const float* uvb = UV + (size_t)bbase * 512;
  const float* vrow = UV + (size_t)p * 512 + 256;
  float4 v4 = *(const float4*)&vrow[lane * 4];
#pragma unroll
  for (int k = 0; k < 12; ++k) {
    int jn = IDX[p * 12 + k];
    const float* urow = uvb + (size_t)jn * 512;
    float4 u4 = *(const float4*)&urow[lane * 4];
    float4 h;
    h.x = fmaxf(u4.x + v4.x, 0.f); h.y = fmaxf(u4.y + v4.y, 0.f);
    h.z = fmaxf(u4.z + v4.z, 0.f); h.w = fmaxf(u4.w + v4.w, 0.f);
    *(float4*)&h1[wave][k][lane * 4] = h;
  }
  __syncthreads();
  float acc[12][4] = {};
  const float* wbase = W2T + lane * 4;
  for (int c0 = 0; c0 < 256; c0 += 4) {
    float4 w0 = *(const float4*)&wbase[(size_t)(c0 + 0) * 256];
    float4 w1 = *(const float4*)&wbase[(size_t)(c0 + 1) * 256];
    float4 w2 = *(const float4*)&wbase[(size_t)(c0 + 2) * 256];
    float4 w3 = *(const float4*)&wbase[(size_t)(c0 + 3) * 256];
#pragma unroll
    for (int k = 0; k < 12; ++k) {
      float4 h = *(const float4*)&h1[wave][k][c0];  // wave-uniform broadcast
      acc[k][0] += h.x * w0.x + h.y * w1.x + h.z * w2.x + h.w * w3.x;
      acc[k][1] += h.x * w0.y + h.y * w1.y + h.z * w2.y + h.w * w3.y;
      acc[k][2] += h.x * w0.z + h.y * w1.z + h.z * w2.z + h.w * w3.z;
      acc[k][3] += h.x * w0.w + h.y * w1.w + h.z * w2.w + h.w * w3.w;
    }
  }
  float4 b4 = *(const float4*)&B2[lane * 4];
  float m0v = acc[0][0], m1v = acc[0][1], m2v = acc[0][2], m3v = acc[0][3];
#pragma unroll
  for (int k = 1; k < 12; ++k) {
    m0v = fmaxf(m0v, acc[k][0]); m1v = fmaxf(m1v, acc[k][1]);
    m2v = fmaxf(m2v, acc[k][2]); m3v = fmaxf(m3v, acc[k][3]);
  }
  float4 o4;
  o4.x = fmaxf(m0v + b4.x, 0.f); o4.y = fmaxf(m1v + b4.y, 0.f);
  o4.z = fmaxf(m2v + b4.z, 0.f); o4.w = fmaxf(m3v + b4.w, 0.f);
  *(float4*)&OUT[(size_t)p * 256 + lane * 4] = o4;
}

// ---------------------------------------------------------------- EC2: gather + relu + sum
__global__ __launch_bounds__(256) void ec2_kernel(
    const float* __restrict__ UV, const int* __restrict__ IDX,
    float* __restrict__ OUT) {
  int wave = threadIdx.x >> 6;
  int lane = threadIdx.x & 63;
  int p = blockIdx.x * 4 + wave;
  int bbase = (p >> 12) << 12;
  const float* uvb = UV + (size_t)bbase * 512;
  const float* vrow = UV + (size_t)p * 512 + 256;
  float4 v4 = *(const float4*)&vrow[lane * 4];
  float4 a4 = {0.f, 0.f, 0.f, 0.f};
#pragma unroll
  for (int k = 0; k < 8; ++k) {
    int jn = IDX[p * 8 + k];
    const float* urow = uvb + (size_t)jn * 512;
    float4 u4 = *(const float4*)&urow[lane * 4];
    a4.x += fmaxf(u4.x + v4.x, 0.f); a4.y += fmaxf(u4.y + v4.y, 0.f);
    a4.z += fmaxf(u4.z + v4.z, 0.f); a4.w += fmaxf(u4.w + v4.w, 0.f);
  }
  *(float4*)&OUT[(size_t)p * 256 + lane * 4] = a4;
}

// ---------------------------------------------------------------- final 64->1
__global__ void final_kernel(const float* __restrict__ X, const float* __restrict__ W,
                             const float* __restrict__ Bb, float* __restrict__ OUT) {
  int p = blockIdx.x * 4 + (threadIdx.x >> 6);
  int lane = threadIdx.x & 63;
  float v = X[(size_t)p * 64 + lane] * W[lane];
#pragma unroll
  for (int off = 32; off >= 1; off >>= 1) v += __shfl_xor(v, off);
  if (lane == 0) OUT[p] = fmaxf(v + Bb[0], 0.f);
}

// ---------------------------------------------------------------- launch
extern "C" void kernel_launch(void* const* d_in, const int* in_sizes, int n_in,
                              void* d_out, int out_size, void* d_ws, size_t ws_size,
                              hipStream_t stream) {
  const float* feature = (const float*)d_in[0];
  const float* conv0_w = (const float*)d_in[1];
  const float* conv0_b = (const float*)d_in[2];
  const float* ec1_w1  = (const float*)d_in[3];
  const float* ec1_b1  = (const float*)d_in[4];
  const float* ec1_w2  = (const float*)d_in[5];
  const float* ec1_b2  = (const float*)d_in[6];
  const float* conv1_w = (const float*)d_in[7];
  const float* conv1_b = (const float*)d_in[8];
  const float* ec2_w   = (const float*)d_in[9];
  const float* ec2_b   = (const float*)d_in[10];
  const float* dec1_w  = (const float*)d_in[11];
  const float* dec1_b  = (const float*)d_in[12];
  const float* dec2_w  = (const float*)d_in[13];
  const float* dec2_b  = (const float*)d_in[14];
  const float* out_w   = (const float*)d_in[15];
  const float* out_b   = (const float*)d_in[16];
  float* out = (float*)d_out;

  char* ws = (char*)d_ws;
  float* wuv1 = (float*)(ws + 0);
  float* buv1 = (float*)(ws + 131072);
  float* wuv2 = (float*)(ws + 133120);
  float* buv2 = (float*)(ws + 264192);
  float* w2t  = (float*)(ws + 266240);
  float* xx   = (float*)(ws + 528384);
  int*   idx  = (int*)  (ws + 659456);
  float* x0   = (float*)(ws + 2232320);   // x0 -> x1c -> xd2
  float* uv   = (float*)(ws + 10620928);  // uv1 -> uv2 -> xd1
  float* x1   = (float*)(ws + 77729792);  // x1 -> x2

  const int P = PTS_TOTAL;

  prep_kernel<<<256, 256, 0, stream>>>(ec1_w1, ec1_b1, ec1_w2, ec2_w, ec2_b,
                                       wuv1, buv1, wuv2, buv2, w2t);
  gemm_rowmajor<true><<<dim3(P / 64, 1), 256, 0, stream>>>(feature, conv0_w, conv0_b, x0, P, 256, 64);
  sqnorm64<<<P / 4, 256, 0, stream>>>(x0, xx);
  knn_kernel<12><<<dim3(NPTS / 64, NBATCH), 256, 0, stream>>>(x0, xx, idx);
  gemm_rowmajor<false><<<dim3(P / 64, 8), 256, 0, stream>>>(x0, wuv1, buv1, uv, P, 64, 512);
  ec1_kernel<<<P / 4, 256, 0, stream>>>(uv, idx, w2t, ec1_b2, x1);
  gemm_rowmajor<true><<<dim3(P / 64, 1), 256, 0, stream>>>(x1, conv1_w, conv1_b, x0, P, 256, 64);
  sqnorm64<<<P / 4, 256, 0, stream>>>(x0, xx);
  knn_kernel<8><<<dim3(NPTS / 64, NBATCH), 256, 0, stream>>>(x0, xx, idx);
  gemm_rowmajor<false><<<dim3(P / 64, 8), 256, 0, stream>>>(x0, wuv2, buv2, uv, P, 64, 512);
  ec2_kernel<<<P / 4, 256, 0, stream>>>(uv, idx, x1);
  float* xd1 = uv;
  gemm_rowmajor<true><<<dim3(P / 64, 2), 256, 0, stream>>>(x1, dec1_w, dec1_b, xd1, P, 256, 128);
  float* xd2 = x0;
  gemm_rowmajor<true><<<dim3(P / 64, 1), 256, 0, stream>>>(xd1, dec2_w, dec2_b, xd2, P, 128, 64);
  final_kernel<<<P / 4, 256, 0, stream>>>(xd2, out_w, out_b, out);
}

// Round 3
// 2280.408 us; speedup vs baseline: 2.2305x; 1.6957x over previous
//
#include <hip/hip_runtime.h>
#include <hip/hip_bf16.h>

// Problem: B=8, N=4096, C=256, c4=64. All fp32. P = B*N = 32768 points.
//
//  x0  = relu(feature @ conv0_w^T + b)            [P,64]
//  idx1 = knn12(x0);  EC1: h1=relu(u1[j]+v1[i]), h2=relu(h1@W2^T+b2), max_k -> x1 [P,256]
//  x1c = relu(x1 @ conv1_w^T + b)                 [P,64]
//  idx2 = knn8(x1c);  EC2: x2 = sum_k relu(u2[j]+v2[i])  [P,256]
//  decoder: 256->128->64->1 (all relu)
//
// u/v decomposition: W=[A|B]: edge(o) = x_j.A[o] + x_i.(B[o]-A[o]) = u[j][o] + v[i][o]

#define PTS_TOTAL 32768
#define NPTS 4096
#define NBATCH 8

// ---------------------------------------------------------------- prep weights
__global__ void prep_kernel(const float* __restrict__ w1, const float* __restrict__ b1,
                            const float* __restrict__ w2,
                            const float* __restrict__ ew, const float* __restrict__ eb,
                            float* __restrict__ wuv1, float* __restrict__ buv1,
                            float* __restrict__ wuv2, float* __restrict__ buv2,
                            float* __restrict__ w2t) {
  int tid = blockIdx.x * 256 + threadIdx.x;
  if (tid < 512 * 64) {
    int o = tid / 64, c = tid % 64;
    int orow = o & 255;
    float a  = w1[orow * 128 + c];
    float bb = w1[orow * 128 + 64 + c];
    wuv1[tid] = (o < 256) ? a : (bb - a);
    float a2  = ew[orow * 128 + c];
    float b2p = ew[orow * 128 + 64 + c];
    wuv2[tid] = (o < 256) ? a2 : (b2p - a2);
  }
  if (tid < 512) {
    buv1[tid] = (tid < 256) ? 0.f : b1[tid - 256];
    buv2[tid] = (tid < 256) ? 0.f : eb[tid - 256];
  }
  if (tid < 65536) {
    int o = tid / 256, c = tid % 256;
    w2t[c * 256 + o] = w2[o * 256 + c];
  }
}

// ---------------------------------------------------------------- generic fp32 GEMM
template<bool RELU>
__global__ __launch_bounds__(256) void gemm_rowmajor(
    const float* __restrict__ A, const float* __restrict__ W,
    const float* __restrict__ bias, float* __restrict__ Cmat,
    int M, int K, int Cout) {
  __shared__ __align__(16) float As[32][68];
  __shared__ __align__(16) float Bs[32][68];
  int m0 = blockIdx.x * 64;
  int n0 = blockIdx.y * 64;
  int tid = threadIdx.x;
  int tx = tid & 15, ty = tid >> 4;
  float acc[4][4] = {};
  for (int k0 = 0; k0 < K; k0 += 32) {
#pragma unroll
    for (int i = 0; i < 2; ++i) {
      int rr = (tid >> 3) + 32 * i;
      int cc = (tid & 7) * 4;
      float4 va = *(const float4*)&A[(size_t)(m0 + rr) * K + k0 + cc];
      float4 vb = *(const float4*)&W[(size_t)(n0 + rr) * K + k0 + cc];
      As[cc + 0][rr] = va.x; As[cc + 1][rr] = va.y; As[cc + 2][rr] = va.z; As[cc + 3][rr] = va.w;
      Bs[cc + 0][rr] = vb.x; Bs[cc + 1][rr] = vb.y; Bs[cc + 2][rr] = vb.z; Bs[cc + 3][rr] = vb.w;
    }
    __syncthreads();
#pragma unroll 8
    for (int k = 0; k < 32; ++k) {
      float4 a4 = *(const float4*)&As[k][ty * 4];
      float4 b4 = *(const float4*)&Bs[k][tx * 4];
      float a[4] = {a4.x, a4.y, a4.z, a4.w};
      float b[4] = {b4.x, b4.y, b4.z, b4.w};
#pragma unroll
      for (int ii = 0; ii < 4; ++ii)
#pragma unroll
        for (int jj = 0; jj < 4; ++jj)
          acc[ii][jj] += a[ii] * b[jj];
    }
    __syncthreads();
  }
  float4 bias4 = *(const float4*)&bias[n0 + tx * 4];
  float bv[4] = {bias4.x, bias4.y, bias4.z, bias4.w};
#pragma unroll
  for (int ii = 0; ii < 4; ++ii) {
    int m = m0 + ty * 4 + ii;
    float4 v4;
    float* vp = (float*)&v4;
#pragma unroll
    for (int jj = 0; jj < 4; ++jj) {
      float v = acc[ii][jj] + bv[jj];
      if (RELU) v = fmaxf(v, 0.f);
      vp[jj] = v;
    }
    *(float4*)&Cmat[(size_t)m * Cout + n0 + tx * 4] = v4;
  }
}

// ---------------------------------------------------------------- squared norms (C=64)
__global__ void sqnorm64(const float* __restrict__ X, float* __restrict__ xx) {
  int p = blockIdx.x * 4 + (threadIdx.x >> 6);
  int lane = threadIdx.x & 63;
  float v = X[(size_t)p * 64 + lane];
  float s = v * v;
#pragma unroll
  for (int off = 32; off >= 1; off >>= 1) s += __shfl_xor(s, off);
  if (lane == 0) xx[p] = s;
}

// ---------------------------------------------------------------- knn v3
// thread = (row, ssel): 1 row x 16 m per tile. acc stays in registers (no Dbuf).
// m-range split across blockIdx.y (2 splits); tiny merge kernel afterwards.
// LDS float4-unit tiles [c4][m], B swizzled m_phys=(m&15)*4+(m>>4) -> conflict-free.
template<int KN>
__global__ __launch_bounds__(256, 4) void knn_kernel(
    const float* __restrict__ X,   // [B][N][64]
    const float* __restrict__ XX,  // [B][N]
    float* __restrict__ outD,      // [2][P][KN]
    int* __restrict__ outI) {      // [2][P][KN]
  __shared__ __align__(16) float smem[16 * 67 * 4 * 2 + 64];
  float4* As4 = (float4*)smem;              // [16 c4][67 pad] rows plain
  float4* Bs4 = ((float4*)smem) + 16 * 67;  // [16 c4][67 pad] m swizzled
  float* xxs = smem + 16 * 67 * 4 * 2;      // [64]
  int tid = threadIdx.x;
  int tx = tid & 15, ty = tid >> 4;         // staging map
  int row = tid >> 2, ssel = tid & 3;       // compute map
  int b = blockIdx.z;
  int split = blockIdx.y;
  int q0 = blockIdx.x * 64;
  int mbase = split * (NPTS / 2);
  const int NT = (NPTS / 2) / 64;
  const float* Xb = X + (size_t)b * NPTS * 64;
  const float* XXb = XX + (size_t)b * NPTS;
  // stage A once: As4[c4][row]
  {
    float4 va[4];
#pragma unroll
    for (int i = 0; i < 4; ++i)
      va[i] = *(const float4*)&Xb[(size_t)(q0 + ty + 16 * i) * 64 + tx * 4];
#pragma unroll
    for (int i = 0; i < 4; ++i)
      As4[tx * 67 + ty + 16 * i] = va[i];
  }
  float bd[KN];
  int bi[KN];
#pragma unroll
  for (int t = 0; t < KN; ++t) { bd[t] = 1e30f; bi[t] = 0x7fffffff; }
  float md = 1e30f;
  int mgi = 0x7fffffff, mslot = 0;
  // prefetch tile 0
  float4 pre[4];
  float prex;
#pragma unroll
  for (int i = 0; i < 4; ++i)
    pre[i] = *(const float4*)&Xb[(size_t)(mbase + ty + 16 * i) * 64 + tx * 4];
  prex = XXb[mbase + (tid & 63)];

  for (int t = 0; t < NT; ++t) {
    int m0 = mbase + t * 64;
    // write staged tile: m = ty+16i -> m_phys = ty*4 + i
#pragma unroll
    for (int i = 0; i < 4; ++i)
      Bs4[tx * 67 + ty * 4 + i] = pre[i];
    if (tid < 64) xxs[tid] = prex;
    // prefetch next tile into regs (hidden under GEMM+select)
    if (t + 1 < NT) {
      int m1 = m0 + 64;
#pragma unroll
      for (int i = 0; i < 4; ++i)
        pre[i] = *(const float4*)&Xb[(size_t)(m1 + ty + 16 * i) * 64 + tx * 4];
      prex = XXb[m1 + (tid & 63)];
    }
    __syncthreads();
    // GEMM: acc[mm] = dot(x_q, x_m), m = ssel*16+mm -> m_phys = mm*4 + ssel
    float acc[16] = {};
#pragma unroll 2
    for (int cc = 0; cc < 16; ++cc) {
      float4 a4 = As4[cc * 67 + row];
#pragma unroll
      for (int mm = 0; mm < 16; ++mm) {
        float4 b4 = Bs4[cc * 67 + mm * 4 + ssel];
        acc[mm] += a4.x * b4.x;
        acc[mm] += a4.y * b4.y;
        acc[mm] += a4.z * b4.z;
        acc[mm] += a4.w * b4.w;
      }
    }
    // select: d = xx[m] - 2*dot. gi monotonic per thread -> ties always lose.
#pragma unroll
    for (int q = 0; q < 4; ++q) {
      float4 xq = *(const float4*)&xxs[ssel * 16 + q * 4];
      float dv[4];
      dv[0] = fmaf(-2.f, acc[q * 4 + 0], xq.x);
      dv[1] = fmaf(-2.f, acc[q * 4 + 1], xq.y);
      dv[2] = fmaf(-2.f, acc[q * 4 + 2], xq.z);
      dv[3] = fmaf(-2.f, acc[q * 4 + 3], xq.w);
      float mn = fminf(fminf(dv[0], dv[1]), fminf(dv[2], dv[3]));
      if (mn < md) {
        int gib = m0 + ssel * 16 + q * 4;
#pragma unroll
        for (int j = 0; j < 4; ++j) {
          if (dv[j] < md) {
            bd[mslot] = dv[j];
            bi[mslot] = gib + j;
            // rescan for new worst (lexicographic max of (d, gi))
            md = bd[0]; mgi = bi[0]; mslot = 0;
#pragma unroll
            for (int t2 = 1; t2 < KN; ++t2) {
              bool g = (bd[t2] > md) || (bd[t2] == md && bi[t2] > mgi);
              if (g) { md = bd[t2]; mgi = bi[t2]; mslot = t2; }
            }
          }
        }
      }
    }
    __syncthreads();
  }
  // sort own list ascending (d, gi) — once per block-run
#pragma unroll
  for (int i = 0; i < KN - 1; ++i)
#pragma unroll
    for (int j = 0; j < KN - 1 - i; ++j) {
      bool sw = (bd[j + 1] < bd[j]) || (bd[j + 1] == bd[j] && bi[j + 1] < bi[j]);
      float td = sw ? bd[j + 1] : bd[j];
      float tD = sw ? bd[j] : bd[j + 1];
      int ti = sw ? bi[j + 1] : bi[j];
      int tI = sw ? bi[j] : bi[j + 1];
      bd[j] = td; bd[j + 1] = tD; bi[j] = ti; bi[j + 1] = tI;
    }
  // merge 4 per-row lists (alias smem; all tile reads done)
  const int S = 4 * KN + 1;
  float* cd = smem;
  int* ci = (int*)(smem + 64 * S);
#pragma unroll
  for (int t = 0; t < KN; ++t) {
    cd[row * S + ssel * KN + t] = bd[t];
    ci[row * S + ssel * KN + t] = bi[t];
  }
  __syncthreads();
  if (ssel == 0) {
    int p0 = 0, p1 = 0, p2 = 0, p3 = 0;
    const float* cdr = cd + row * S;
    const int* cir = ci + row * S;
    size_t pg = (size_t)b * NPTS + q0 + row;
    float* oD = outD + ((size_t)split * PTS_TOTAL + pg) * KN;
    int* oI = outI + ((size_t)split * PTS_TOTAL + pg) * KN;
    for (int r = 0; r < KN; ++r) {
      float d0 = cdr[0 * KN + p0], d1 = cdr[1 * KN + p1];
      float d2 = cdr[2 * KN + p2], d3 = cdr[3 * KN + p3];
      int i0 = cir[0 * KN + p0], i1 = cir[1 * KN + p1];
      int i2 = cir[2 * KN + p2], i3 = cir[3 * KN + p3];
      int sel = 0; float bdd = d0; int bii = i0;
      if (d1 < bdd || (d1 == bdd && i1 < bii)) { sel = 1; bdd = d1; bii = i1; }
      if (d2 < bdd || (d2 == bdd && i2 < bii)) { sel = 2; bdd = d2; bii = i2; }
      if (d3 < bdd || (d3 == bdd && i3 < bii)) { sel = 3; bdd = d3; bii = i3; }
      oD[r] = bdd; oI[r] = bii;
      if (sel == 0) ++p0; else if (sel == 1) ++p1; else if (sel == 2) ++p2; else ++p3;
    }
  }
}

// ---------------------------------------------------------------- merge 2 split lists
template<int KN>
__global__ void merge_splits_kernel(const float* __restrict__ D, const int* __restrict__ I,
                                    int* __restrict__ IDX) {
  int p = blockIdx.x * 256 + threadIdx.x;
  const float* d0 = D + (size_t)p * KN;
  const float* d1 = D + ((size_t)PTS_TOTAL + p) * KN;
  const int* i0 = I + (size_t)p * KN;
  const int* i1 = I + ((size_t)PTS_TOTAL + p) * KN;
  int* op = IDX + (size_t)p * KN;
  int a = 0, c = 0;
#pragma unroll
  for (int r = 0; r < KN; ++r) {
    float da = d0[a], dc = d1[c];
    int ia = i0[a], ic = i1[c];
    bool t = (dc < da) || (dc == da && ic < ia);
    op[r] = t ? ic : ia;
    if (t) ++c; else ++a;
  }
}

// ---------------------------------------------------------------- EC1: gather + MLP2 + max
__global__ __launch_bounds__(256) void ec1_kernel(
    const float* __restrict__ UV,   // [P][512] (u | v+b1)
    const int* __restrict__ IDX,    // [P][12]
    const float* __restrict__ W2T,  // [256 c][256 o]
    const float* __restrict__ B2,   // [256]
    float* __restrict__ OUT) {      // [P][256]
  __shared__ __align__(16) float h1[4][12][256];
  int wave = threadIdx.x >> 6;
  int lane = threadIdx.x & 63;
  int p = blockIdx.x * 4 + wave;
  int bbase = (p >> 12) << 12;  // batch start point
  const float* uvb = UV + (size_t)bbase * 512;
  const float* vrow = UV + (size_t)p * 512 + 256;
  float4 v4 = *(const float4*)&vrow[lane * 4];
#pragma unroll
  for (int k = 0; k < 12; ++k) {
    int jn = IDX[p * 12 + k];
    const float* urow = uvb + (size_t)jn * 512;
    float4 u4 = *(const float4*)&urow[lane * 4];
    float4 h;
    h.x = fmaxf(u4.x + v4.x, 0.f); h.y = fmaxf(u4.y + v4.y, 0.f);
    h.z = fmaxf(u4.z + v4.z, 0.f); h.w = fmaxf(u4.w + v4.w, 0.f);
    *(float4*)&h1[wave][k][lane * 4] = h;
  }
  __syncthreads();
  float acc[12][4] = {};
  const float* wbase = W2T + lane * 4;
  for (int c0 = 0; c0 < 256; c0 += 4) {
    float4 w0 = *(const float4*)&wbase[(size_t)(c0 + 0) * 256];
    float4 w1 = *(const float4*)&wbase[(size_t)(c0 + 1) * 256];
    float4 w2 = *(const float4*)&wbase[(size_t)(c0 + 2) * 256];
    float4 w3 = *(const float4*)&wbase[(size_t)(c0 + 3) * 256];
#pragma unroll
    for (int k = 0; k < 12; ++k) {
      float4 h = *(const float4*)&h1[wave][k][c0];  // wave-uniform broadcast
      acc[k][0] += h.x * w0.x + h.y * w1.x + h.z * w2.x + h.w * w3.x;
      acc[k][1] += h.x * w0.y + h.y * w1.y + h.z * w2.y + h.w * w3.y;
      acc[k][2] += h.x * w0.z + h.y * w1.z + h.z * w2.z + h.w * w3.z;
      acc[k][3] += h.x * w0.w + h.y * w1.w + h.z * w2.w + h.w * w3.w;
    }
  }
  float4 b4 = *(const float4*)&B2[lane * 4];
  float m0v = acc[0][0], m1v = acc[0][1], m2v = acc[0][2], m3v = acc[0][3];
#pragma unroll
  for (int k = 1; k < 12; ++k) {
    m0v = fmaxf(m0v, acc[k][0]); m1v = fmaxf(m1v, acc[k][1]);
    m2v = fmaxf(m2v, acc[k][2]); m3v = fmaxf(m3v, acc[k][3]);
  }
  float4 o4;
  o4.x = fmaxf(m0v + b4.x, 0.f); o4.y = fmaxf(m1v + b4.y, 0.f);
  o4.z = fmaxf(m2v + b4.z, 0.f); o4.w = fmaxf(m3v + b4.w, 0.f);
  *(float4*)&OUT[(size_t)p * 256 + lane * 4] = o4;
}

// ---------------------------------------------------------------- EC2: gather + relu + sum
__global__ __launch_bounds__(256) void ec2_kernel(
    const float* __restrict__ UV, const int* __restrict__ IDX,
    float* __restrict__ OUT) {
  int wave = threadIdx.x >> 6;
  int lane = threadIdx.x & 63;
  int p = blockIdx.x * 4 + wave;
  int bbase = (p >> 12) << 12;
  const float* uvb = UV + (size_t)bbase * 512;
  const float* vrow = UV + (size_t)p * 512 + 256;
  float4 v4 = *(const float4*)&vrow[lane * 4];
  float4 a4 = {0.f, 0.f, 0.f, 0.f};
#pragma unroll
  for (int k = 0; k < 8; ++k) {
    int jn = IDX[p * 8 + k];
    const float* urow = uvb + (size_t)jn * 512;
    float4 u4 = *(const float4*)&urow[lane * 4];
    a4.x += fmaxf(u4.x + v4.x, 0.f); a4.y += fmaxf(u4.y + v4.y, 0.f);
    a4.z += fmaxf(u4.z + v4.z, 0.f); a4.w += fmaxf(u4.w + v4.w, 0.f);
  }
  *(float4*)&OUT[(size_t)p * 256 + lane * 4] = a4;
}

// ---------------------------------------------------------------- final 64->1
__global__ void final_kernel(const float* __restrict__ X, const float* __restrict__ W,
                             const float* __restrict__ Bb, float* __restrict__ OUT) {
  int p = blockIdx.x * 4 + (threadIdx.x >> 6);
  int lane = threadIdx.x & 63;
  float v = X[(size_t)p * 64 + lane] * W[lane];
#pragma unroll
  for (int off = 32; off >= 1; off >>= 1) v += __shfl_xor(v, off);
  if (lane == 0) OUT[p] = fmaxf(v + Bb[0], 0.f);
}

// ---------------------------------------------------------------- launch
extern "C" void kernel_launch(void* const* d_in, const int* in_sizes, int n_in,
                              void* d_out, int out_size, void* d_ws, size_t ws_size,
                              hipStream_t stream) {
  const float* feature = (const float*)d_in[0];
  const float* conv0_w = (const float*)d_in[1];
  const float* conv0_b = (const float*)d_in[2];
  const float* ec1_w1  = (const float*)d_in[3];
  const float* ec1_b1  = (const float*)d_in[4];
  const float* ec1_w2  = (const float*)d_in[5];
  const float* ec1_b2  = (const float*)d_in[6];
  const float* conv1_w = (const float*)d_in[7];
  const float* conv1_b = (const float*)d_in[8];
  const float* ec2_w   = (const float*)d_in[9];
  const float* ec2_b   = (const float*)d_in[10];
  const float* dec1_w  = (const float*)d_in[11];
  const float* dec1_b  = (const float*)d_in[12];
  const float* dec2_w  = (const float*)d_in[13];
  const float* dec2_b  = (const float*)d_in[14];
  const float* out_w   = (const float*)d_in[15];
  const float* out_b   = (const float*)d_in[16];
  float* out = (float*)d_out;

  char* ws = (char*)d_ws;
  float* wuv1 = (float*)(ws + 0);
  float* buv1 = (float*)(ws + 131072);
  float* wuv2 = (float*)(ws + 133120);
  float* buv2 = (float*)(ws + 264192);
  float* w2t  = (float*)(ws + 266240);
  float* xx   = (float*)(ws + 528384);
  int*   idx  = (int*)  (ws + 659456);
  float* x0   = (float*)(ws + 2232320);   // x0 -> x1c -> xd2
  float* uv   = (float*)(ws + 10620928);  // knnD/knnI -> uv1 -> knnD/knnI -> uv2 -> xd1
  float* x1   = (float*)(ws + 77729792);  // x1 -> x2

  // knn scratch lives inside the (currently dead) uv region
  float* knnD = (float*)(ws + 10620928);
  int*   knnI = (int*)(ws + 10620928 + 3145728);

  const int P = PTS_TOTAL;

  prep_kernel<<<256, 256, 0, stream>>>(ec1_w1, ec1_b1, ec1_w2, ec2_w, ec2_b,
                                       wuv1, buv1, wuv2, buv2, w2t);
  gemm_rowmajor<true><<<dim3(P / 64, 1), 256, 0, stream>>>(feature, conv0_w, conv0_b, x0, P, 256, 64);
  sqnorm64<<<P / 4, 256, 0, stream>>>(x0, xx);
  knn_kernel<12><<<dim3(NPTS / 64, 2, NBATCH), 256, 0, stream>>>(x0, xx, knnD, knnI);
  merge_splits_kernel<12><<<P / 256, 256, 0, stream>>>(knnD, knnI, idx);
  gemm_rowmajor<false><<<dim3(P / 64, 8), 256, 0, stream>>>(x0, wuv1, buv1, uv, P, 64, 512);
  ec1_kernel<<<P / 4, 256, 0, stream>>>(uv, idx, w2t, ec1_b2, x1);
  gemm_rowmajor<true><<<dim3(P / 64, 1), 256, 0, stream>>>(x1, conv1_w, conv1_b, x0, P, 256, 64);
  sqnorm64<<<P / 4, 256, 0, stream>>>(x0, xx);
  knn_kernel<8><<<dim3(NPTS / 64, 2, NBATCH), 256, 0, stream>>>(x0, xx, knnD, knnI);
  merge_splits_kernel<8><<<P / 256, 256, 0, stream>>>(knnD, knnI, idx);
  gemm_rowmajor<false><<<dim3(P / 64, 8), 256, 0, stream>>>(x0, wuv2, buv2, uv, P, 64, 512);
  ec2_kernel<<<P / 4, 256, 0, stream>>>(uv, idx, x1);
  float* xd1 = uv;
  gemm_rowmajor<true><<<dim3(P / 64, 2), 256, 0, stream>>>(x1, dec1_w, dec1_b, xd1, P, 256, 128);
  float* xd2 = x0;
  gemm_rowmajor<true><<<dim3(P / 64, 1), 256, 0, stream>>>(xd1, dec2_w, dec2_b, xd2, P, 128, 64);
  final_kernel<<<P / 4, 256, 0, stream>>>(xd2, out_w, out_b, out);
}